// Round 1
// 408.442 us; speedup vs baseline: 1.0042x; 1.0042x over previous
//
#include <hip/hip_runtime.h>
#include <hip/hip_bf16.h>
#include <math.h>

#define ALPHA 0.01f

typedef __bf16 bf16x8 __attribute__((ext_vector_type(8)));
typedef float  floatx4 __attribute__((ext_vector_type(4)));

static __device__ __forceinline__ unsigned short f2bf_bits(float f) {
    return __builtin_bit_cast(unsigned short, (__bf16)f);   // RNE
}

// async global->LDS, 16 B per lane, zero destination VGPRs.
static __device__ __forceinline__ void glds16(const void* g, void* l) {
    __builtin_amdgcn_global_load_lds(
        (const __attribute__((address_space(1))) unsigned int*)g,
        (__attribute__((address_space(3))) unsigned int*)l, 16, 0, 0);
}

// 16-lane (DPP row) reductions — pure VALU, no LDS traffic.
template <int CTRL>
static __device__ __forceinline__ float dppmov(float x) {
    int r = __builtin_amdgcn_update_dpp(0, __builtin_bit_cast(int, x), CTRL, 0xf, 0xf, false);
    return __builtin_bit_cast(float, r);
}
static __device__ __forceinline__ float red16min(float x) {
    x = fminf(x, dppmov<0x121>(x)); x = fminf(x, dppmov<0x122>(x));
    x = fminf(x, dppmov<0x124>(x)); x = fminf(x, dppmov<0x128>(x));
    return x;
}
static __device__ __forceinline__ float red16max(float x) {
    x = fmaxf(x, dppmov<0x121>(x)); x = fmaxf(x, dppmov<0x122>(x));
    x = fmaxf(x, dppmov<0x124>(x)); x = fmaxf(x, dppmov<0x128>(x));
    return x;
}
static __device__ __forceinline__ float red16sum(float x) {
    x += dppmov<0x121>(x); x += dppmov<0x122>(x);
    x += dppmov<0x124>(x); x += dppmov<0x128>(x);
    return x;
}

// ---------------------------------------------------------------------------
// Layer 1 (unchanged R6 structure): Y(bf16) = leaky_relu(X@W1^T + b1) + entropy.
// Per-block entropy partial plain-stored to Hpart[blockIdx].
// ---------------------------------------------------------------------------
template <int DIN, int DOUT, bool XF32, bool WRES, int MINB>
__global__ __launch_bounds__(256, MINB) void layer_mfma(
    const void* __restrict__ Xin, const unsigned short* __restrict__ Wf,
    const float* __restrict__ bias, unsigned short* __restrict__ Y,
    float* __restrict__ Hpart)
{
    constexpr int CTN     = DOUT / 16;
    constexpr int KT_FULL = DIN / 32;
    constexpr int TAIL    = DIN % 32;            // L1: 16
    constexpr int HALF    = DOUT / 2;
    constexpr int LOG2D   = (DOUT == 256) ? 8 : (DOUT == 128) ? 7 : 5;
    constexpr float LOGB  = (DOUT == 256) ? 5.54517744f
                          : (DOUT == 128) ? 4.85203026f : 3.46573590f;
    constexpr int XBYTES  = WRES ? 16 : 64 * 32 * (XF32 ? 4 : 2);
    constexpr int WBYTES  = WRES ? (size_t)DIN * DOUT * 2 : DOUT * 64;
    constexpr int WSLOTS  = (DIN / 32) * CTN * 64;
    static_assert(DOUT % 32 == 0 && DOUT <= 256, "DOUT");
    static_assert(XF32 || TAIL == 0, "bf16 input requires DIN%32==0");

    __shared__ __align__(16) char smemX[XBYTES];
    __shared__ __align__(16) char smemW[WBYTES];
    __shared__ unsigned int counts[16][HALF + 1];
    __shared__ float hsum[4];

    const int t      = threadIdx.x;
    const int lane   = t & 63;
    const int lane16 = lane & 15;
    const int q      = lane >> 4;
    const int w      = t >> 6;
    const int row0   = blockIdx.x * 64;
    const int myrow  = w * 16 + lane16;

    float biasr[CTN];
    #pragma unroll
    for (int ct = 0; ct < CTN; ct++) biasr[ct] = bias[ct * 16 + lane16];

    floatx4 acc[CTN];
    #pragma unroll
    for (int ct = 0; ct < CTN; ct++) acc[ct] = (floatx4)(0.0f);

    if constexpr (WRES) {
        static_assert(WSLOTS % 256 == 0, "WSLOTS");
        #pragma unroll
        for (int i = 0; i < WSLOTS / 256; i++)
            glds16(Wf + ((size_t)(i * 256 + w * 64 + lane)) * 8,
                   smemW + (i * 256 + w * 64) * 16);
        __syncthreads();

        const unsigned short* X = (const unsigned short*)Xin;
        const size_t abase = (size_t)(row0 + myrow) * DIN + q * 8;
        bf16x8 acur = *(const bf16x8*)(X + abase);
        #pragma unroll
        for (int kt = 0; kt < KT_FULL; kt++) {
            bf16x8 anxt = acur;
            if (kt + 1 < KT_FULL)
                anxt = *(const bf16x8*)(X + abase + (kt + 1) * 32);
            #pragma unroll
            for (int ct = 0; ct < CTN; ct++) {
                bf16x8 bw = *(const bf16x8*)(smemW + ((kt * CTN + ct) * 64 + lane) * 16);
                acc[ct] = __builtin_amdgcn_mfma_f32_16x16x32_bf16(acur, bw, acc[ct], 0, 0, 0);
            }
            acur = anxt;
        }
    } else {
        auto stageW = [&](int kt) {
            #pragma unroll
            for (int j = w; j < CTN; j += 4)
                glds16(Wf + ((size_t)kt * CTN * 64 + j * 64 + lane) * 8,
                       smemW + j * 64 * 16);
        };
        auto stageX = [&](int kt) {
            const float* X = (const float*)Xin;
            #pragma unroll
            for (int j = 0; j < 2; j++) {
                int s  = w * 128 + j * 64 + lane;
                int gc = (s & ~7) | ((s ^ (s >> 3)) & 7);
                int r  = gc >> 3, c = gc & 7;
                glds16(X + (size_t)(row0 + r) * DIN + kt * 32 + c * 4,
                       smemX + (w * 128 + j * 64) * 16);
            }
        };
        auto compute = [&]() {
            int s0 = myrow * 8 + (((2 * q)     ^ myrow) & 7);
            int s1 = myrow * 8 + (((2 * q + 1) ^ myrow) & 7);
            float4 f0 = *(const float4*)(smemX + s0 * 16);
            float4 f1 = *(const float4*)(smemX + s1 * 16);
            uint4 pk;
            pk.x = (unsigned)f2bf_bits(f0.x) | ((unsigned)f2bf_bits(f0.y) << 16);
            pk.y = (unsigned)f2bf_bits(f0.z) | ((unsigned)f2bf_bits(f0.w) << 16);
            pk.z = (unsigned)f2bf_bits(f1.x) | ((unsigned)f2bf_bits(f1.y) << 16);
            pk.w = (unsigned)f2bf_bits(f1.z) | ((unsigned)f2bf_bits(f1.w) << 16);
            bf16x8 a = __builtin_bit_cast(bf16x8, pk);
            #pragma unroll
            for (int ct = 0; ct < CTN; ct++) {
                bf16x8 bw = *(const bf16x8*)(smemW + (ct * 64 + lane) * 16);
                acc[ct] = __builtin_amdgcn_mfma_f32_16x16x32_bf16(a, bw, acc[ct], 0, 0, 0);
            }
        };

        #pragma unroll 1
        for (int kt = 0; kt < KT_FULL; kt++) {
            __syncthreads();
            stageX(kt);
            stageW(kt);
            __syncthreads();
            compute();
        }
        if constexpr (TAIL > 0) {
            __syncthreads();
            stageW(KT_FULL);
            {
                const float* X = (const float*)Xin;
                int r = t >> 2, c = t & 3;
                float4 v = *(const float4*)(X + (size_t)(row0 + r) * DIN
                                            + KT_FULL * 32 + c * 4);
                *(float4*)(smemX + (r * 8 + ((c ^ r) & 7)) * 16) = v;
                int c2 = c + 4;
                *(float4*)(smemX + (r * 8 + ((c2 ^ r) & 7)) * 16)
                    = make_float4(0.f, 0.f, 0.f, 0.f);
            }
            __syncthreads();
            compute();
        }
    }

    #pragma unroll
    for (int ct = 0; ct < CTN; ct++) {
        #pragma unroll
        for (int reg = 0; reg < 4; reg++) {
            float v = acc[ct][reg] + biasr[ct];
            v = v > 0.0f ? v : ALPHA * v;
            acc[ct][reg] = v;
            Y[(size_t)(row0 + w * 16 + q * 4 + reg) * DOUT
              + ct * 16 + lane16] = f2bf_bits(v);
        }
    }

    unsigned int* cc = counts[w * 4 + q];
    float Hq = 0.0f;
    #pragma unroll
    for (int reg = 0; reg < 4; reg++) {
        float mn = acc[0][reg], mx = mn;
        #pragma unroll
        for (int ct = 1; ct < CTN; ct++) {
            mn = fminf(mn, acc[ct][reg]);
            mx = fmaxf(mx, acc[ct][reg]);
        }
        mn = red16min(mn);
        mx = red16max(mx);
        float wdt = mx - mn;
        float scale = (float)DOUT / (wdt > 0.0f ? wdt : 1.0f);

        #pragma unroll
        for (int i = 0; i < DOUT / 32; i++) cc[lane16 + 16 * i] = 0u;

        #pragma unroll
        for (int ct = 0; ct < CTN; ct++) {
            int b = (int)((acc[ct][reg] - mn) * scale);
            b = b < (DOUT - 1) ? b : (DOUT - 1);
            atomicAdd(&cc[b & (HALF - 1)],
                      1u << (((b >> (LOG2D - 1)) & 1) << 4));
        }

        float s = 0.0f;
        #pragma unroll
        for (int i = 0; i < DOUT / 32; i++) {
            unsigned int word = cc[lane16 + 16 * i];
            int c0 = (int)(word & 0xffffu), c1 = (int)(word >> 16);
            if (c0 > 0) { float p = (float)c0 * (1.0f / (float)DOUT); s += p * __logf(p); }
            if (c1 > 0) { float p = (float)c1 * (1.0f / (float)DOUT); s += p * __logf(p); }
        }
        s = red16sum(s);
        Hq += LOGB - s;
    }
    Hq += __shfl_xor(Hq, 16, 64);
    Hq += __shfl_xor(Hq, 32, 64);

    if (lane == 0) hsum[w] = Hq;
    __syncthreads();
    if (t == 0) Hpart[blockIdx.x] = hsum[0] + hsum[1] + hsum[2] + hsum[3];
}

// ---------------------------------------------------------------------------
// Fused tail: one 16-row wave tile flows L2->L3->L4->L5->L6 with NO barriers.
// A-frags: L2 from global bufA; L3..L6 from a per-wave XOR-swizzled LDS tile
// (16-B chunk c stored at c ^ (row & (NC-1)) -> conflict-free ds_read_b128).
// B-frags: straight from global Wf slots (L1/L2-cached, fully coalesced).
// Returns the wave's entropy partial for the layer.
// ---------------------------------------------------------------------------
template <int DIN, int DOUT, bool AG>
static __device__ __forceinline__ float tail_layer(
    const unsigned short* __restrict__ Ag, size_t arow,
    char* __restrict__ yt,
    const unsigned short* __restrict__ Wf, const float* __restrict__ bias,
    unsigned int* __restrict__ cc, int lane)
{
    constexpr int KT  = DIN / 32, CTN = DOUT / 16;
    constexpr int NCI = DIN / 8,  NCO = DOUT / 8;     // 16-B chunks per row
    constexpr int HALF  = DOUT / 2;
    constexpr int LOG2D = (DOUT == 128) ? 7 : 5;
    constexpr float LOGB = (DOUT == 128) ? 4.85203026f : 3.46573590f;
    const int lane16 = lane & 15, q = lane >> 4;

    bf16x8 a[KT];
    if constexpr (AG) {
        #pragma unroll
        for (int kt = 0; kt < KT; kt++)
            a[kt] = *(const bf16x8*)(Ag + arow + q * 8 + kt * 32);
    } else {
        // previous layer's ds_writes precede these reads (in-wave DS order);
        // the asm fence also stops the compiler reordering across the alias.
        asm volatile("s_waitcnt lgkmcnt(0)" ::: "memory");
        #pragma unroll
        for (int kt = 0; kt < KT; kt++) {
            int cs = (kt * 4 + q) ^ (lane16 & (NCI - 1));
            a[kt] = *(const bf16x8*)(yt + lane16 * (DIN * 2) + cs * 16);
        }
    }

    float biasr[CTN];
    #pragma unroll
    for (int ct = 0; ct < CTN; ct++) biasr[ct] = bias[ct * 16 + lane16];

    floatx4 acc[CTN];
    #pragma unroll
    for (int ct = 0; ct < CTN; ct++) acc[ct] = (floatx4)(0.0f);

    #pragma unroll
    for (int kt = 0; kt < KT; kt++) {
        #pragma unroll
        for (int ct = 0; ct < CTN; ct++) {
            bf16x8 bw = *(const bf16x8*)(Wf + ((size_t)(kt * CTN + ct) * 64 + lane) * 8);
            acc[ct] = __builtin_amdgcn_mfma_f32_16x16x32_bf16(a[kt], bw, acc[ct], 0, 0, 0);
        }
    }

    // epilogue: bias + leaky_relu; write swizzled LDS tile for next layer
    #pragma unroll
    for (int ct = 0; ct < CTN; ct++) {
        #pragma unroll
        for (int reg = 0; reg < 4; reg++) {
            float v = acc[ct][reg] + biasr[ct];
            v = v > 0.0f ? v : ALPHA * v;
            acc[ct][reg] = v;
            int r  = q * 4 + reg;
            int c  = (ct * 16 + lane16) >> 3;
            int cs = c ^ (r & (NCO - 1));
            *(unsigned short*)(yt + r * (DOUT * 2) + cs * 16 + (lane16 & 7) * 2)
                = f2bf_bits(v);
        }
    }

    // entropy: quad q owns rows q*4 + reg
    float Hq = 0.0f;
    #pragma unroll
    for (int reg = 0; reg < 4; reg++) {
        float mn = acc[0][reg], mx = mn;
        #pragma unroll
        for (int ct = 1; ct < CTN; ct++) {
            mn = fminf(mn, acc[ct][reg]);
            mx = fmaxf(mx, acc[ct][reg]);
        }
        mn = red16min(mn);
        mx = red16max(mx);
        float wdt = mx - mn;
        float scale = (float)DOUT / (wdt > 0.0f ? wdt : 1.0f);

        #pragma unroll
        for (int i = 0; i < DOUT / 32; i++) cc[lane16 + 16 * i] = 0u;
        // in-wave DS program order: zeros -> atomics -> reads

        #pragma unroll
        for (int ct = 0; ct < CTN; ct++) {
            int b = (int)((acc[ct][reg] - mn) * scale);
            b = b < (DOUT - 1) ? b : (DOUT - 1);
            atomicAdd(&cc[b & (HALF - 1)],
                      1u << (((b >> (LOG2D - 1)) & 1) << 4));
        }

        float s = 0.0f;
        #pragma unroll
        for (int i = 0; i < DOUT / 32; i++) {
            unsigned int word = cc[lane16 + 16 * i];
            int c0 = (int)(word & 0xffffu), c1 = (int)(word >> 16);
            if (c0 > 0) { float p = (float)c0 * (1.0f / (float)DOUT); s += p * __logf(p); }
            if (c1 > 0) { float p = (float)c1 * (1.0f / (float)DOUT); s += p * __logf(p); }
        }
        s = red16sum(s);
        Hq += LOGB - s;
    }
    Hq += __shfl_xor(Hq, 16, 64);
    Hq += __shfl_xor(Hq, 32, 64);
    return Hq;
}

__global__ __launch_bounds__(256, 3) void tail_fused(
    const unsigned short* __restrict__ Xb,
    const unsigned short* __restrict__ W2f, const float* __restrict__ b2,
    const unsigned short* __restrict__ W3f, const float* __restrict__ b3,
    const unsigned short* __restrict__ W4f, const float* __restrict__ b4,
    const unsigned short* __restrict__ W5f, const float* __restrict__ b5,
    const float* __restrict__ W6, const float* __restrict__ b6,
    float* __restrict__ out, float* __restrict__ Hpart)
{
    __shared__ __align__(16) char yts[4][16 * 128 * 2];   // per-wave Y tile
    __shared__ unsigned int counts[16][65];               // per-(wave,quad)

    const int t = threadIdx.x;
    const int lane = t & 63, lane16 = lane & 15, q = lane >> 4, w = t >> 6;
    char* yt = yts[w];
    unsigned int* cc = counts[w * 4 + q];
    const int row0 = blockIdx.x * 64 + w * 16;            // wave's first row
    const size_t arow = (size_t)(row0 + lane16) * 256;
    const int hidx = blockIdx.x * 4 + w;

    float H;
    H = tail_layer<256, 128, true >(Xb, arow, yt, W2f, b2, cc, lane);
    if (lane == 0) Hpart[1 * 4096 + hidx] = H;
    H = tail_layer<128, 128, false>(Xb, 0, yt, W3f, b3, cc, lane);
    if (lane == 0) Hpart[2 * 4096 + hidx] = H;
    H = tail_layer<128, 128, false>(Xb, 0, yt, W4f, b4, cc, lane);
    if (lane == 0) Hpart[3 * 4096 + hidx] = H;
    H = tail_layer<128,  32, false>(Xb, 0, yt, W5f, b5, cc, lane);
    if (lane == 0) Hpart[4 * 4096 + hidx] = H;

    // ---- L6: out = log_softmax(relu(x @ W6^T + b6)); row = lane16,
    //      outputs j split across quads (3,3,3,1). ----
    asm volatile("s_waitcnt lgkmcnt(0)" ::: "memory");
    float x[32];
    #pragma unroll
    for (int c = 0; c < 4; c++) {
        int cs = c ^ (lane16 & 3);
        bf16x8 v = *(const bf16x8*)(yt + lane16 * 64 + cs * 16);
        #pragma unroll
        for (int j = 0; j < 8; j++) x[c * 8 + j] = (float)v[j];
    }

    float z[3];
    float m = -1e30f;
    #pragma unroll
    for (int s2 = 0; s2 < 3; s2++) {
        int jj = q * 3 + s2;
        float a6 = 0.0f;
        if (jj < 10) {
            a6 = b6[jj];
            #pragma unroll
            for (int k = 0; k < 32; k++) a6 = fmaf(x[k], W6[jj * 32 + k], a6);
            a6 = fmaxf(a6, 0.0f);
            m = fmaxf(m, a6);
        }
        z[s2] = a6;
    }
    m = fmaxf(m, __shfl_xor(m, 16, 64));
    m = fmaxf(m, __shfl_xor(m, 32, 64));
    float se = 0.0f;
    #pragma unroll
    for (int s2 = 0; s2 < 3; s2++)
        if (q * 3 + s2 < 10) se += __expf(z[s2] - m);
    se += __shfl_xor(se, 16, 64);
    se += __shfl_xor(se, 32, 64);
    float ls = __logf(se);
    const size_t ro = (size_t)(row0 + lane16) * 10;
    #pragma unroll
    for (int s2 = 0; s2 < 3; s2++) {
        int jj = q * 3 + s2;
        if (jj < 10) out[ro + jj] = z[s2] - m - ls;
    }
}

// ---------------------------------------------------------------------------
// fp32 W1..W5 -> bf16 fragment-major slots, concatenated into ws. (unchanged)
// ---------------------------------------------------------------------------
__global__ void convert_wfrag(const float* __restrict__ W1, const float* __restrict__ W2,
                              const float* __restrict__ W3, const float* __restrict__ W4,
                              const float* __restrict__ W5, unsigned short* __restrict__ out)
{
    int s = blockIdx.x * 256 + threadIdx.x;
    if (s >= 34304) return;
    const float* W; int DIN, CTN, sl;
    if      (s < 25600) { W = W1; DIN = 784; CTN = 16; sl = s;         }
    else if (s < 29696) { W = W2; DIN = 256; CTN = 8;  sl = s - 25600; }
    else if (s < 31744) { W = W3; DIN = 128; CTN = 8;  sl = s - 29696; }
    else if (s < 33792) { W = W4; DIN = 128; CTN = 8;  sl = s - 31744; }
    else                { W = W5; DIN = 128; CTN = 2;  sl = s - 33792; }
    int kt = sl / (CTN * 64);
    int ct = (sl / 64) % CTN;
    int ln = sl & 63;
    int r  = ct * 16 + (ln & 15);
    int k0 = kt * 32 + (ln >> 4) * 8;
    unsigned short v[8];
    #pragma unroll
    for (int j = 0; j < 8; j++) {
        int k = k0 + j;
        v[j] = (k < DIN) ? f2bf_bits(W[(size_t)r * DIN + k]) : (unsigned short)0;
    }
    uint4 pk;
    pk.x = (unsigned)v[0] | ((unsigned)v[1] << 16);
    pk.y = (unsigned)v[2] | ((unsigned)v[3] << 16);
    pk.z = (unsigned)v[4] | ((unsigned)v[5] << 16);
    pk.w = (unsigned)v[6] | ((unsigned)v[7] << 16);
    *(uint4*)(out + (size_t)s * 8) = pk;
}

// ---------------------------------------------------------------------------
// Final entropy reduction: block l sums layer l's partials -> out_tail[l].
// Layer 0 has 1024 block-level partials (from L1); layers 1-4 have 4096
// wave-level partials (from tail_fused).
// ---------------------------------------------------------------------------
__global__ __launch_bounds__(256) void hreduce(const float* __restrict__ Hp,
                                               float* __restrict__ out_tail)
{
    __shared__ float sm[4];
    const int t = threadIdx.x, lane = t & 63, w = t >> 6;
    const int l = blockIdx.x;
    const int n = l ? 4096 : 1024;
    const float* p = Hp + (size_t)l * 4096;
    float s = 0.0f;
    for (int i = t; i < n; i += 256) s += p[i];
    #pragma unroll
    for (int off = 1; off <= 32; off <<= 1) s += __shfl_xor(s, off, 64);
    if (lane == 0) sm[w] = s;
    __syncthreads();
    if (t == 0)
        out_tail[l] = (sm[0] + sm[1] + sm[2] + sm[3]) * (1.0f / 65536.0f);
}

// ---------------------------------------------------------------------------
extern "C" void kernel_launch(void* const* d_in, const int* in_sizes, int n_in,
                              void* d_out, int out_size, void* d_ws, size_t ws_size,
                              hipStream_t stream)
{
    const float* x  = (const float*)d_in[0];
    const float* W1 = (const float*)d_in[1];  const float* b1 = (const float*)d_in[2];
    const float* W2 = (const float*)d_in[3];  const float* b2 = (const float*)d_in[4];
    const float* W3 = (const float*)d_in[5];  const float* b3 = (const float*)d_in[6];
    const float* W4 = (const float*)d_in[7];  const float* b4 = (const float*)d_in[8];
    const float* W5 = (const float*)d_in[9];  const float* b5 = (const float*)d_in[10];
    const float* W6 = (const float*)d_in[11]; const float* b6 = (const float*)d_in[12];
    float* out = (float*)d_out;

    constexpr int B = 65536;
    char* ws = (char*)d_ws;
    float* Hpart = (float*)ws;                             // 5*4096 floats = 80 KB
    unsigned short* Wfrag = (unsigned short*)(ws + 81920); // 34304 slots * 16 B
    unsigned short* W1f = Wfrag;                           // 25600 slots
    unsigned short* W2f = W1f + 25600 * 8;
    unsigned short* W3f = W2f + 4096 * 8;
    unsigned short* W4f = W3f + 2048 * 8;
    unsigned short* W5f = W4f + 2048 * 8;
    unsigned short* bufA = (unsigned short*)(ws + (1 << 20));  // B*256 bf16

    convert_wfrag<<<134, 256, 0, stream>>>(W1, W2, W3, W4, W5, Wfrag);

    layer_mfma<784, 256, true, false, 4><<<B / 64, 256, 0, stream>>>(
        x, W1f, b1, bufA, Hpart);

    tail_fused<<<B / 64, 256, 0, stream>>>(
        bufA, W2f, b2, W3f, b3, W4f, b4, W5f, b5, W6, b6, out, Hpart);

    hreduce<<<5, 256, 0, stream>>>(Hpart, out + (size_t)B * 10);
}

// Round 2
// 401.556 us; speedup vs baseline: 1.0215x; 1.0171x over previous
//
#include <hip/hip_runtime.h>
#include <hip/hip_bf16.h>
#include <math.h>

#define ALPHA 0.01f

typedef __bf16 bf16x8 __attribute__((ext_vector_type(8)));
typedef float  floatx4 __attribute__((ext_vector_type(4)));

static __device__ __forceinline__ unsigned short f2bf_bits(float f) {
    return __builtin_bit_cast(unsigned short, (__bf16)f);   // RNE
}
static __device__ __forceinline__ float bf2f(unsigned short u) {
    return __builtin_bit_cast(float, (unsigned)u << 16);    // exact
}

// async global->LDS, 16 B per lane, zero destination VGPRs.
static __device__ __forceinline__ void glds16(const void* g, void* l) {
    __builtin_amdgcn_global_load_lds(
        (const __attribute__((address_space(1))) unsigned int*)g,
        (__attribute__((address_space(3))) unsigned int*)l, 16, 0, 0);
}

// 16-lane (DPP row) reductions — pure VALU, no LDS traffic.
template <int CTRL>
static __device__ __forceinline__ float dppmov(float x) {
    int r = __builtin_amdgcn_update_dpp(0, __builtin_bit_cast(int, x), CTRL, 0xf, 0xf, false);
    return __builtin_bit_cast(float, r);
}
static __device__ __forceinline__ float red16min(float x) {
    x = fminf(x, dppmov<0x121>(x)); x = fminf(x, dppmov<0x122>(x));
    x = fminf(x, dppmov<0x124>(x)); x = fminf(x, dppmov<0x128>(x));
    return x;
}
static __device__ __forceinline__ float red16max(float x) {
    x = fmaxf(x, dppmov<0x121>(x)); x = fmaxf(x, dppmov<0x122>(x));
    x = fmaxf(x, dppmov<0x124>(x)); x = fmaxf(x, dppmov<0x128>(x));
    return x;
}
static __device__ __forceinline__ float red16sum(float x) {
    x += dppmov<0x121>(x); x += dppmov<0x122>(x);
    x += dppmov<0x124>(x); x += dppmov<0x128>(x);
    return x;
}

// ---------------------------------------------------------------------------
// Histogram entropy of a wave's 16-row tile held in acc[CTN] (post-activation).
// Quad q owns rows q*4+reg. cc = this quad's private row (>=128 words usable).
// Returns wave-summed H (valid in all lanes).
// ---------------------------------------------------------------------------
template <int DOUT>
static __device__ __forceinline__ float entropy_tile(const floatx4* acc,
        unsigned int* cc, int lane16)
{
    constexpr int CTN   = DOUT / 16;
    constexpr int HALF  = DOUT / 2;
    constexpr int LOG2D = (DOUT == 256) ? 8 : (DOUT == 128) ? 7 : 5;
    constexpr float LOGB = (DOUT == 256) ? 5.54517744f
                         : (DOUT == 128) ? 4.85203026f : 3.46573590f;
    float Hq = 0.0f;
    #pragma unroll
    for (int reg = 0; reg < 4; reg++) {
        float mn = acc[0][reg], mx = mn;
        #pragma unroll
        for (int ct = 1; ct < CTN; ct++) {
            mn = fminf(mn, acc[ct][reg]);
            mx = fmaxf(mx, acc[ct][reg]);
        }
        mn = red16min(mn);
        mx = red16max(mx);
        float wdt = mx - mn;
        float scale = (float)DOUT / (wdt > 0.0f ? wdt : 1.0f);

        #pragma unroll
        for (int i = 0; i < DOUT / 32; i++) cc[lane16 + 16 * i] = 0u;
        // in-wave DS program order: zeros -> atomics -> reads

        #pragma unroll
        for (int ct = 0; ct < CTN; ct++) {
            int b = (int)((acc[ct][reg] - mn) * scale);
            b = b < (DOUT - 1) ? b : (DOUT - 1);
            atomicAdd(&cc[b & (HALF - 1)],
                      1u << (((b >> (LOG2D - 1)) & 1) << 4));
        }

        float s = 0.0f;
        #pragma unroll
        for (int i = 0; i < DOUT / 32; i++) {
            unsigned int word = cc[lane16 + 16 * i];
            int c0 = (int)(word & 0xffffu), c1 = (int)(word >> 16);
            if (c0 > 0) { float p = (float)c0 * (1.0f / (float)DOUT); s += p * __logf(p); }
            if (c1 > 0) { float p = (float)c1 * (1.0f / (float)DOUT); s += p * __logf(p); }
        }
        s = red16sum(s);
        Hq += LOGB - s;
    }
    Hq += __shfl_xor(Hq, 16, 64);
    Hq += __shfl_xor(Hq, 32, 64);
    return Hq;
}

// ---------------------------------------------------------------------------
// One tail layer: acc = A @ W^T (+bias, leaky), write swizzled yt for the next
// layer, return entropy partial. A-frags supplied by caller (regs).
// B-frags straight from global Wf slots (L1/L2-cached, coalesced).
// ---------------------------------------------------------------------------
template <int DIN, int DOUT>
static __device__ __forceinline__ float tail_layer(const bf16x8* a,
    char* __restrict__ yt,
    const unsigned short* __restrict__ Wf, const float* __restrict__ bias,
    unsigned int* __restrict__ cc, int lane)
{
    constexpr int KT = DIN / 32, CTN = DOUT / 16, NCO = DOUT / 8;
    const int lane16 = lane & 15, q = lane >> 4;

    floatx4 acc[CTN];
    #pragma unroll
    for (int ct = 0; ct < CTN; ct++) acc[ct] = (floatx4)(0.0f);

    #pragma unroll
    for (int kt = 0; kt < KT; kt++) {
        #pragma unroll
        for (int ct = 0; ct < CTN; ct++) {
            bf16x8 bw = *(const bf16x8*)(Wf + ((size_t)(kt * CTN + ct) * 64 + lane) * 8);
            acc[ct] = __builtin_amdgcn_mfma_f32_16x16x32_bf16(a[kt], bw, acc[ct], 0, 0, 0);
        }
    }

    #pragma unroll
    for (int ct = 0; ct < CTN; ct++) {
        float bb = bias[ct * 16 + lane16];
        #pragma unroll
        for (int reg = 0; reg < 4; reg++) {
            float v = acc[ct][reg] + bb;
            v = v > 0.0f ? v : ALPHA * v;
            acc[ct][reg] = v;
            int r  = q * 4 + reg;
            int c  = (ct * 16 + lane16) >> 3;
            int cs = c ^ (r & (NCO - 1));
            *(unsigned short*)(yt + r * (DOUT * 2) + cs * 16 + (lane16 & 7) * 2)
                = f2bf_bits(v);
        }
    }
    return entropy_tile<DOUT>(acc, cc, lane16);
}

// Load A-frags for a DIN-wide layer from the wave's swizzled yt tile.
template <int DIN>
static __device__ __forceinline__ void load_afrags(bf16x8* a,
    const char* __restrict__ yt, int lane16, int q)
{
    constexpr int KT = DIN / 32, NCI = DIN / 8;
    // previous layer's ds_writes precede these reads (in-wave DS order);
    // the asm fence also stops the compiler reordering across the alias.
    asm volatile("s_waitcnt lgkmcnt(0)" ::: "memory");
    #pragma unroll
    for (int kt = 0; kt < KT; kt++) {
        int cs = (kt * 4 + q) ^ (lane16 & (NCI - 1));
        a[kt] = *(const bf16x8*)(yt + lane16 * (DIN * 2) + cs * 16);
    }
    asm volatile("s_waitcnt lgkmcnt(0)" ::: "memory");
}

// ---------------------------------------------------------------------------
// Megakernel: L1 (staged 2-barrier MFMA loop) -> intra-wave transpose ->
// barrier-free L2..L5 -> L6 log_softmax. One block = 64 rows.
// LDS reuse: regA = {smemX 8K + smemW 16K (L1)} then {yts 4x4K (tail)};
// cnt[16][129] shared by all layers' entropy (quad-private rows).
// ---------------------------------------------------------------------------
__global__ __launch_bounds__(256, 4) void mega(
    const float* __restrict__ X,
    const unsigned short* __restrict__ W1f, const float* __restrict__ b1,
    const unsigned short* __restrict__ W2f, const float* __restrict__ b2,
    const unsigned short* __restrict__ W3f, const float* __restrict__ b3,
    const unsigned short* __restrict__ W4f, const float* __restrict__ b4,
    const unsigned short* __restrict__ W5f, const float* __restrict__ b5,
    const float* __restrict__ W6, const float* __restrict__ b6,
    float* __restrict__ out, float* __restrict__ Hpart)
{
    __shared__ __align__(16) char regA[24576];
    __shared__ unsigned int cnt[16][129];
    __shared__ float hsum[4];

    const int t = threadIdx.x;
    const int lane = t & 63, lane16 = lane & 15, q = lane >> 4, w = t >> 6;
    const int row0 = blockIdx.x * 64;
    const int myrow = w * 16 + lane16;
    unsigned int* cc = cnt[w * 4 + q];
    char* yt = regA + w * 4096;          // valid after the post-L1 barrier

    // ================= L1: 784 -> 256 (staged, 2-barrier loop) =============
    floatx4 acc1[16];
    #pragma unroll
    for (int ct = 0; ct < 16; ct++) acc1[ct] = (floatx4)(0.0f);
    {
        constexpr int DIN = 784, CTN = 16, KT_FULL = 24;   // tail k=768..784
        char* smemX = regA;              // 64 rows * 8 swizzled 16B chunks
        char* smemW = regA + 8192;       // 16 ct * 64 slots * 16B

        auto stageW = [&](int kt) {
            #pragma unroll
            for (int j = w; j < CTN; j += 4)
                glds16(W1f + ((size_t)kt * CTN * 64 + j * 64 + lane) * 8,
                       smemW + j * 64 * 16);
        };
        auto stageX = [&](int kt) {
            #pragma unroll
            for (int j = 0; j < 2; j++) {
                int s  = w * 128 + j * 64 + lane;
                int gc = (s & ~7) | ((s ^ (s >> 3)) & 7); // swizzled global src
                int r  = gc >> 3, c = gc & 7;
                glds16(X + (size_t)(row0 + r) * DIN + kt * 32 + c * 4,
                       smemX + (w * 128 + j * 64) * 16);
            }
        };
        auto compute = [&]() {
            int s0 = myrow * 8 + (((2 * q)     ^ myrow) & 7);
            int s1 = myrow * 8 + (((2 * q + 1) ^ myrow) & 7);
            float4 f0 = *(const float4*)(smemX + s0 * 16);
            float4 f1 = *(const float4*)(smemX + s1 * 16);
            uint4 pk;
            pk.x = (unsigned)f2bf_bits(f0.x) | ((unsigned)f2bf_bits(f0.y) << 16);
            pk.y = (unsigned)f2bf_bits(f0.z) | ((unsigned)f2bf_bits(f0.w) << 16);
            pk.z = (unsigned)f2bf_bits(f1.x) | ((unsigned)f2bf_bits(f1.y) << 16);
            pk.w = (unsigned)f2bf_bits(f1.z) | ((unsigned)f2bf_bits(f1.w) << 16);
            bf16x8 a = __builtin_bit_cast(bf16x8, pk);
            #pragma unroll
            for (int ct = 0; ct < CTN; ct++) {
                bf16x8 bw = *(const bf16x8*)(smemW + (ct * 64 + lane) * 16);
                acc1[ct] = __builtin_amdgcn_mfma_f32_16x16x32_bf16(a, bw, acc1[ct], 0, 0, 0);
            }
        };

        #pragma unroll 1
        for (int kt = 0; kt < KT_FULL; kt++) {
            __syncthreads();
            stageX(kt);
            stageW(kt);
            __syncthreads();
            compute();
        }
        // tail ktile: k = 768..784 (W slots zero-padded)
        __syncthreads();
        stageW(KT_FULL);
        {
            int r = t >> 2, c = t & 3;
            float4 v = *(const float4*)(X + (size_t)(row0 + r) * DIN
                                        + KT_FULL * 32 + c * 4);
            *(float4*)(smemX + (r * 8 + ((c ^ r) & 7)) * 16) = v;
            int c2 = c + 4;
            *(float4*)(smemX + (r * 8 + ((c2 ^ r) & 7)) * 16)
                = make_float4(0.f, 0.f, 0.f, 0.f);
        }
        __syncthreads();
        compute();
    }

    // epilogue: bias + leaky_relu in registers (no global store)
    #pragma unroll
    for (int ct = 0; ct < 16; ct++) {
        float bb = b1[ct * 16 + lane16];
        #pragma unroll
        for (int reg = 0; reg < 4; reg++) {
            float v = acc1[ct][reg] + bb;
            acc1[ct][reg] = v > 0.0f ? v : ALPHA * v;
        }
    }

    float H1 = entropy_tile<256>(acc1, cc, lane16);
    if (lane == 0) hsum[w] = H1;
    __syncthreads();     // hsum ready AND all waves done with smemX/smemW
    if (t == 0) Hpart[blockIdx.x] = hsum[0] + hsum[1] + hsum[2] + hsum[3];

    // ===== intra-wave transpose: L1 C-layout -> L2 A-frags, 2 half-passes ===
    // (yt holds 128 cols per pass; in-wave lgkmcnt fences order write->read
    //  and read->overwrite; no cross-wave traffic.)
    bf16x8 a2[8];
    #pragma unroll
    for (int p = 0; p < 2; p++) {
        #pragma unroll
        for (int ct = 0; ct < 8; ct++) {
            #pragma unroll
            for (int reg = 0; reg < 4; reg++) {
                int r  = q * 4 + reg;
                int c  = (ct * 16 + lane16) >> 3;     // chunk within half
                int cs = c ^ r;                       // NCI=16 -> r&15 == r
                *(unsigned short*)(yt + r * 256 + cs * 16 + (lane16 & 7) * 2)
                    = f2bf_bits(acc1[p * 8 + ct][reg]);
            }
        }
        asm volatile("s_waitcnt lgkmcnt(0)" ::: "memory");
        #pragma unroll
        for (int kt = 0; kt < 4; kt++) {
            int cs = (kt * 4 + q) ^ lane16;
            a2[p * 4 + kt] = *(const bf16x8*)(yt + lane16 * 256 + cs * 16);
        }
        asm volatile("s_waitcnt lgkmcnt(0)" ::: "memory");
    }

    // ================= L2..L5: barrier-free chain ==========================
    float H = tail_layer<256, 128>(a2, yt, W2f, b2, cc, lane);
    if (lane == 0) Hpart[1 * 4096 + blockIdx.x * 4 + w] = H;

    bf16x8 a[4];
    load_afrags<128>(a, yt, lane16, q);
    H = tail_layer<128, 128>(a, yt, W3f, b3, cc, lane);
    if (lane == 0) Hpart[2 * 4096 + blockIdx.x * 4 + w] = H;

    load_afrags<128>(a, yt, lane16, q);
    H = tail_layer<128, 128>(a, yt, W4f, b4, cc, lane);
    if (lane == 0) Hpart[3 * 4096 + blockIdx.x * 4 + w] = H;

    load_afrags<128>(a, yt, lane16, q);
    H = tail_layer<128, 32>(a, yt, W5f, b5, cc, lane);
    if (lane == 0) Hpart[4 * 4096 + blockIdx.x * 4 + w] = H;

    // ================= L6: log_softmax(relu(x @ W6^T + b6)) ================
    // row = lane16 of this wave's tile; outputs j split across quads (3,3,3,1)
    asm volatile("s_waitcnt lgkmcnt(0)" ::: "memory");
    float x6[32];
    #pragma unroll
    for (int c = 0; c < 4; c++) {
        int cs = c ^ (lane16 & 3);
        bf16x8 v = *(const bf16x8*)(yt + lane16 * 64 + cs * 16);
        #pragma unroll
        for (int j = 0; j < 8; j++) x6[c * 8 + j] = (float)v[j];
    }

    float z[3];
    float m = -1e30f;
    #pragma unroll
    for (int s2 = 0; s2 < 3; s2++) {
        int jj = q * 3 + s2;
        float a6 = 0.0f;
        if (jj < 10) {
            a6 = b6[jj];
            #pragma unroll
            for (int k = 0; k < 32; k++) a6 = fmaf(x6[k], W6[jj * 32 + k], a6);
            a6 = fmaxf(a6, 0.0f);
            m = fmaxf(m, a6);
        }
        z[s2] = a6;
    }
    m = fmaxf(m, __shfl_xor(m, 16, 64));
    m = fmaxf(m, __shfl_xor(m, 32, 64));
    float se = 0.0f;
    #pragma unroll
    for (int s2 = 0; s2 < 3; s2++)
        if (q * 3 + s2 < 10) se += __expf(z[s2] - m);
    se += __shfl_xor(se, 16, 64);
    se += __shfl_xor(se, 32, 64);
    float ls = __logf(se);
    const size_t ro = (size_t)(row0 + w * 16 + lane16) * 10;
    #pragma unroll
    for (int s2 = 0; s2 < 3; s2++) {
        int jj = q * 3 + s2;
        if (jj < 10) out[ro + jj] = z[s2] - m - ls;
    }
}

// ---------------------------------------------------------------------------
// fp32 W1..W5 -> bf16 fragment-major slots, concatenated into ws. (unchanged)
// ---------------------------------------------------------------------------
__global__ void convert_wfrag(const float* __restrict__ W1, const float* __restrict__ W2,
                              const float* __restrict__ W3, const float* __restrict__ W4,
                              const float* __restrict__ W5, unsigned short* __restrict__ out)
{
    int s = blockIdx.x * 256 + threadIdx.x;
    if (s >= 34304) return;
    const float* W; int DIN, CTN, sl;
    if      (s < 25600) { W = W1; DIN = 784; CTN = 16; sl = s;         }
    else if (s < 29696) { W = W2; DIN = 256; CTN = 8;  sl = s - 25600; }
    else if (s < 31744) { W = W3; DIN = 128; CTN = 8;  sl = s - 29696; }
    else if (s < 33792) { W = W4; DIN = 128; CTN = 8;  sl = s - 31744; }
    else                { W = W5; DIN = 128; CTN = 2;  sl = s - 33792; }
    int kt = sl / (CTN * 64);
    int ct = (sl / 64) % CTN;
    int ln = sl & 63;
    int r  = ct * 16 + (ln & 15);
    int k0 = kt * 32 + (ln >> 4) * 8;
    unsigned short v[8];
    #pragma unroll
    for (int j = 0; j < 8; j++) {
        int k = k0 + j;
        v[j] = (k < DIN) ? f2bf_bits(W[(size_t)r * DIN + k]) : (unsigned short)0;
    }
    uint4 pk;
    pk.x = (unsigned)v[0] | ((unsigned)v[1] << 16);
    pk.y = (unsigned)v[2] | ((unsigned)v[3] << 16);
    pk.z = (unsigned)v[4] | ((unsigned)v[5] << 16);
    pk.w = (unsigned)v[6] | ((unsigned)v[7] << 16);
    *(uint4*)(out + (size_t)s * 8) = pk;
}

// ---------------------------------------------------------------------------
// Final entropy reduction: block l sums layer l's partials -> out_tail[l].
// Layer 0: 1024 block-level partials; layers 1-4: 4096 wave-level partials.
// ---------------------------------------------------------------------------
__global__ __launch_bounds__(256) void hreduce(const float* __restrict__ Hp,
                                               float* __restrict__ out_tail)
{
    __shared__ float sm[4];
    const int t = threadIdx.x, lane = t & 63, w = t >> 6;
    const int l = blockIdx.x;
    const int n = l ? 4096 : 1024;
    const float* p = Hp + (size_t)l * 4096;
    float s = 0.0f;
    for (int i = t; i < n; i += 256) s += p[i];
    #pragma unroll
    for (int off = 1; off <= 32; off <<= 1) s += __shfl_xor(s, off, 64);
    if (lane == 0) sm[w] = s;
    __syncthreads();
    if (t == 0)
        out_tail[l] = (sm[0] + sm[1] + sm[2] + sm[3]) * (1.0f / 65536.0f);
}

// ---------------------------------------------------------------------------
extern "C" void kernel_launch(void* const* d_in, const int* in_sizes, int n_in,
                              void* d_out, int out_size, void* d_ws, size_t ws_size,
                              hipStream_t stream)
{
    const float* x  = (const float*)d_in[0];
    const float* W1 = (const float*)d_in[1];  const float* b1 = (const float*)d_in[2];
    const float* W2 = (const float*)d_in[3];  const float* b2 = (const float*)d_in[4];
    const float* W3 = (const float*)d_in[5];  const float* b3 = (const float*)d_in[6];
    const float* W4 = (const float*)d_in[7];  const float* b4 = (const float*)d_in[8];
    const float* W5 = (const float*)d_in[9];  const float* b5 = (const float*)d_in[10];
    const float* W6 = (const float*)d_in[11]; const float* b6 = (const float*)d_in[12];
    float* out = (float*)d_out;

    constexpr int B = 65536;
    char* ws = (char*)d_ws;
    float* Hpart = (float*)ws;                             // 5*4096 floats = 80 KB
    unsigned short* Wfrag = (unsigned short*)(ws + 81920); // 34304 slots * 16 B
    unsigned short* W1f = Wfrag;                           // 25600 slots
    unsigned short* W2f = W1f + 25600 * 8;
    unsigned short* W3f = W2f + 4096 * 8;
    unsigned short* W4f = W3f + 2048 * 8;
    unsigned short* W5f = W4f + 2048 * 8;

    convert_wfrag<<<134, 256, 0, stream>>>(W1, W2, W3, W4, W5, Wfrag);

    mega<<<B / 64, 256, 0, stream>>>(
        x, W1f, b1, W2f, b2, W3f, b3, W4f, b4, W5f, b5, W6, b6, out, Hpart);

    hreduce<<<5, 256, 0, stream>>>(Hpart, out + (size_t)B * 10);
}